// Round 1
// 1094.679 us; speedup vs baseline: 1.7116x; 1.7116x over previous
//
#include <hip/hip_runtime.h>

#define EPS 1e-12f
#define NEG_INF (-3.0e38f)

constexpr int B = 128;     // queries
constexpr int D = 128;     // dim
constexpr int K_TOP = 10;
constexpr int TILE_N = 128;

typedef _Float16 half8 __attribute__((ext_vector_type(8)));
typedef _Float16 half4v __attribute__((ext_vector_type(4)));
typedef float f32x4 __attribute__((ext_vector_type(4)));

// monotone float -> uint key (order-preserving, never 0 for real floats)
__device__ inline unsigned fkey(float f) {
    unsigned u = __float_as_uint(f);
    return u ^ (((int)u >> 31) | 0x80000000u);
}
__device__ inline float kinv(unsigned k) {
    unsigned u = k ^ (((int)(~k) >> 31) | 0x80000000u);
    return __uint_as_float(u);
}

// ---------------- 1. query prep: normalize, split fp16 hi/lo, fragment layout ----------------
// grid: B blocks x 64 threads (one wave per query row).
// Output layout: for MFMA frag fi = (row>>4)*4 + (k>>5), lane l' = ((k>>3)&3)*16 + (row&15),
// elem j = k&7  ->  half index fi*512 + l'*8 + j. GEMM loads this with one dwordx4 per lane.
__global__ void qprep_kernel(const float* __restrict__ q, _Float16* __restrict__ qA) {
    int r = blockIdx.x, l = threadIdx.x;
    float2 v = *(const float2*)(q + r * D + 2 * l);
    float s = v.x * v.x + v.y * v.y;
#pragma unroll
    for (int off = 32; off > 0; off >>= 1) s += __shfl_xor(s, off);
    float iv = 1.0f / fmaxf(sqrtf(s), EPS);
    float qx = v.x * iv, qy = v.y * iv;
    _Float16 hx = (_Float16)qx, hy = (_Float16)qy;
    _Float16 lx = (_Float16)(qx - (float)hx), ly = (_Float16)(qy - (float)hy);
    int k = 2 * l;
    int o = ((r >> 4) * 4 + (k >> 5)) * 512 + ((k >> 3) & 3) * 128 + ((r & 15) << 3) + (k & 7);
    _Float16* qhi = qA;
    _Float16* qlo = qA + 16384;
    qhi[o] = hx; qhi[o + 1] = hy;
    qlo[o] = lx; qlo[o + 1] = ly;
}

// ---------------- 2. zero the tilemax keys ----------------
__global__ void initkeys_kernel(unsigned* __restrict__ keys, int total) {
    int i = blockIdx.x * 256 + threadIdx.x;
    int stride = gridDim.x * 256;
    for (; i < total; i += stride) keys[i] = 0u;
}

// ---------------- 3. similarity GEMM: split-fp16 MFMA, fused per-tile row max ----------------
// block: 256 threads (4 waves), tile 128(q) x 128(db), K=128 (4 MFMA K-steps).
// Wave w owns query rows [w*32, w*32+32): mi in {0,1} M-blocks, nj in 0..7 N-blocks.
// A (queries) hi/lo resident in registers; B (db tile) converted fp32->hi/lo in LDS,
// rows XOR-swizzled (byte ^= (row&7)<<4) to kill the 16-way D=128 bank conflict.
__global__ __launch_bounds__(256, 2)
void simgemm_kernel(const _Float16* __restrict__ qA, const float* __restrict__ db,
                    float* __restrict__ sim, unsigned* __restrict__ keys,
                    int N, int ngroups, int gshift) {
    __shared__ _Float16 Bhi[TILE_N * 128];
    __shared__ _Float16 Blo[TILE_N * 128];
    __shared__ float inv_db[TILE_N];

    const int t = threadIdx.x;
    const int l = t & 63, w = t >> 6;
    const int n0 = blockIdx.x * TILE_N;

    // A fragments -> registers (qA is L2-hot after first touch)
    const half8* qhi = (const half8*)qA;       // 2048 half8
    const half8* qlo = qhi + 2048;
    half8 ahi[2][4], alo[2][4];
#pragma unroll
    for (int mi = 0; mi < 2; ++mi)
#pragma unroll
        for (int ks = 0; ks < 4; ++ks) {
            int fi = (w * 2 + mi) * 4 + ks;
            ahi[mi][ks] = qhi[fi * 64 + l];
            alo[mi][ks] = qlo[fi * 64 + l];
        }

    // stage db tile: coalesced fp32 reads, hi/lo split, row inv-norms via 32-lane reduce
#pragma unroll
    for (int it = 0; it < 16; ++it) {
        int f = t + 256 * it;                  // float4 index
        int row = f >> 5, c4 = f & 31;
        int gr = n0 + row;
        float4 v = make_float4(0.f, 0.f, 0.f, 0.f);
        if (gr < N) v = *(const float4*)(db + (size_t)gr * D + c4 * 4);
        float s = v.x * v.x + v.y * v.y + v.z * v.z + v.w * v.w;
        s += __shfl_xor(s, 1);  s += __shfl_xor(s, 2);  s += __shfl_xor(s, 4);
        s += __shfl_xor(s, 8);  s += __shfl_xor(s, 16);
        if ((t & 31) == 0) inv_db[row] = 1.0f / fmaxf(sqrtf(s), EPS);
        _Float16 h0 = (_Float16)v.x, h1 = (_Float16)v.y, h2 = (_Float16)v.z, h3 = (_Float16)v.w;
        half4v hh = {h0, h1, h2, h3};
        half4v ll = {(_Float16)(v.x - (float)h0), (_Float16)(v.y - (float)h1),
                     (_Float16)(v.z - (float)h2), (_Float16)(v.w - (float)h3)};
        int addr = (row * 256 + c4 * 8) ^ ((row & 7) << 4);
        *(half4v*)((char*)Bhi + addr) = hh;
        *(half4v*)((char*)Blo + addr) = ll;
    }
    __syncthreads();

    const int cmod = l & 15, rgrp = l >> 4;
    f32x4 acc[2][8];
#pragma unroll
    for (int mi = 0; mi < 2; ++mi)
#pragma unroll
        for (int nj = 0; nj < 8; ++nj) acc[mi][nj] = (f32x4){0.f, 0.f, 0.f, 0.f};

#pragma unroll
    for (int ks = 0; ks < 4; ++ks) {
#pragma unroll
        for (int nj = 0; nj < 8; ++nj) {
            int nl = nj * 16 + cmod;           // B frag: col = l&15, k = ks*32 + (l>>4)*8
            int addr = (nl * 256 + ks * 64 + rgrp * 16) ^ ((nl & 7) << 4);
            half8 bh = *(const half8*)((const char*)Bhi + addr);
            half8 bl = *(const half8*)((const char*)Blo + addr);
#pragma unroll
            for (int mi = 0; mi < 2; ++mi) {
                acc[mi][nj] = __builtin_amdgcn_mfma_f32_16x16x32_f16(alo[mi][ks], bh, acc[mi][nj], 0, 0, 0);
                acc[mi][nj] = __builtin_amdgcn_mfma_f32_16x16x32_f16(ahi[mi][ks], bl, acc[mi][nj], 0, 0, 0);
                acc[mi][nj] = __builtin_amdgcn_mfma_f32_16x16x32_f16(ahi[mi][ks], bh, acc[mi][nj], 0, 0, 0);
            }
        }
    }

    // epilogue: scale by db inv-norm, store sim, per-row tile max -> atomic key
    float inv[8];
#pragma unroll
    for (int nj = 0; nj < 8; ++nj) inv[nj] = inv_db[nj * 16 + cmod];

    const int grp = blockIdx.x >> gshift;
#pragma unroll
    for (int mi = 0; mi < 2; ++mi) {
#pragma unroll
        for (int r = 0; r < 4; ++r) {
            const int row = w * 32 + mi * 16 + rgrp * 4 + r;   // C: row=(l>>4)*4+reg
            float rowmax = NEG_INF;
            float* srow = sim + (size_t)row * N;
#pragma unroll
            for (int nj = 0; nj < 8; ++nj) {
                int gn = n0 + nj * 16 + cmod;                  // C: col=l&15
                float val = acc[mi][nj][r] * inv[nj];
                if (gn < N) { srow[gn] = val; rowmax = fmaxf(rowmax, val); }
            }
#pragma unroll
            for (int off = 8; off > 0; off >>= 1)
                rowmax = fmaxf(rowmax, __shfl_xor(rowmax, off));
            if (cmod == 0)
                atomicMax(&keys[(size_t)row * ngroups + grp], fkey(rowmax));
        }
    }
}

// ---------------- 4. top-k: threshold from group maxima, scan only qualifying groups ----------------
// grid: B blocks (one per query) x 256 threads.
__global__ __launch_bounds__(256)
void topk_kernel(const float* __restrict__ sim, const unsigned* __restrict__ keys,
                 float* __restrict__ out_idx, int N, int ngroups, int gshift) {
    const int q = blockIdx.x, t = threadIdx.x;
    const unsigned* krow = keys + (size_t)q * ngroups;
    const float* srow = sim + (size_t)q * N;

    // ---- pass A: T = 10th-largest group max (T <= v10, so filter is exact-safe) ----
    unsigned kv[10];
#pragma unroll
    for (int j = 0; j < 10; ++j) kv[j] = 0;
    for (int gi = t; gi < ngroups; gi += 256) {
        unsigned x = krow[gi];
        if (x > kv[9]) {
#pragma unroll
            for (int j = 9; j >= 1; --j) {
                if (kv[j - 1] < x)      kv[j] = kv[j - 1];
                else if (kv[j] < x)     kv[j] = x;
            }
            if (kv[0] < x)              kv[0] = x;
        }
    }
    __shared__ unsigned skv[2560];
#pragma unroll
    for (int j = 0; j < 10; ++j) skv[t * 10 + j] = kv[j];
    __syncthreads();
    __shared__ unsigned srv[256];
    __shared__ int srs[256];
    unsigned Tkey = 0;
    for (int r = 0; r < K_TOP; ++r) {
        unsigned bv = 0; int bslot = t * 10;
#pragma unroll
        for (int j = 0; j < 10; ++j) {
            int s2 = t * 10 + j;
            if (skv[s2] > bv) { bv = skv[s2]; bslot = s2; }
        }
        srv[t] = bv; srs[t] = bslot;
        __syncthreads();
        for (int s2 = 128; s2 > 0; s2 >>= 1) {
            if (t < s2 && srv[t + s2] > srv[t]) { srv[t] = srv[t + s2]; srs[t] = srs[t + s2]; }
            __syncthreads();
        }
        Tkey = srv[0];
        if (t == 0) skv[srs[0]] = 0;
        __syncthreads();
    }
    float Tf = (Tkey == 0) ? NEG_INF : kinv(Tkey);   // Tkey==0 only if ngroups<10 (tiny-ws fallback)

    // ---- pass B: scan qualifying groups, collect (val,idx) candidates >= Tf ----
    float cv[10]; int ci[10];
#pragma unroll
    for (int j = 0; j < 10; ++j) { cv[j] = NEG_INF; ci[j] = 0x7fffffff; }
    const int gcols = TILE_N << gshift;
    for (int gi = t; gi < ngroups; gi += 256) {
        if (krow[gi] >= Tkey) {
            int c0 = gi * gcols;
            int c1 = min(c0 + gcols, N);
            for (int c = c0; c < c1; c += 4) {
                float4 x4 = *(const float4*)(srow + c);
#pragma unroll
                for (int cc = 0; cc < 4; ++cc) {
                    float xv = (cc == 0) ? x4.x : (cc == 1) ? x4.y : (cc == 2) ? x4.z : x4.w;
                    if (xv >= Tf && xv > cv[9]) {
                        int n = c + cc;
#pragma unroll
                        for (int j = 9; j >= 1; --j) {
                            if (cv[j - 1] < xv)      { cv[j] = cv[j - 1]; ci[j] = ci[j - 1]; }
                            else if (cv[j] < xv)     { cv[j] = xv;        ci[j] = n;         }
                        }
                        if (cv[0] < xv)              { cv[0] = xv;        ci[0] = n;         }
                    }
                }
            }
        }
    }

    // ---- block merge with stable tie-break (lower index wins), emit indices ----
    __shared__ float lv[2560];
    __shared__ int   li[2560];
#pragma unroll
    for (int j = 0; j < 10; ++j) { lv[t * 10 + j] = cv[j]; li[t * 10 + j] = ci[j]; }
    __syncthreads();
    __shared__ float rv[256];
    __shared__ int   ri[256];
    __shared__ int   rs2[256];
    for (int r = 0; r < K_TOP; ++r) {
        float bv = NEG_INF; int bi = 0x7fffffff; int bslot = t * 10;
#pragma unroll
        for (int j = 0; j < 10; ++j) {
            int s2 = t * 10 + j;
            float vv = lv[s2]; int ii = li[s2];
            if (vv > bv || (vv == bv && ii < bi)) { bv = vv; bi = ii; bslot = s2; }
        }
        rv[t] = bv; ri[t] = bi; rs2[t] = bslot;
        __syncthreads();
        for (int s2 = 128; s2 > 0; s2 >>= 1) {
            if (t < s2) {
                if (rv[t + s2] > rv[t] || (rv[t + s2] == rv[t] && ri[t + s2] < ri[t])) {
                    rv[t] = rv[t + s2]; ri[t] = ri[t + s2]; rs2[t] = rs2[t + s2];
                }
            }
            __syncthreads();
        }
        if (t == 0) {
            out_idx[q * K_TOP + r] = (float)ri[0];
            lv[rs2[0]] = NEG_INF;
        }
        __syncthreads();
    }
}

extern "C" void kernel_launch(void* const* d_in, const int* in_sizes, int n_in,
                              void* d_out, int out_size, void* d_ws, size_t ws_size,
                              hipStream_t stream) {
    const float* vec = (const float*)d_in[0];   // [B, D] fp32
    const float* db  = (const float*)d_in[1];   // [N, D] fp32
    const int N  = in_sizes[1] / D;             // 1,000,000
    const int NT = (N + TILE_N - 1) / TILE_N;   // 7813 tiles

    float* out_idx = (float*)d_out;             // [B, K_TOP] indices (as float)
    float* sim     = (float*)d_out + B * K_TOP; // [B, N] similarities

    _Float16* qA   = (_Float16*)d_ws;                       // 64 KB: hi[16384] + lo[16384]
    unsigned* keys = (unsigned*)((char*)d_ws + 65536);      // [B][ngroups] monotone keys

    // adapt tile-group granularity to available workspace (g = 2^gshift tiles per group)
    int gshift = 0, ngroups = NT;
    while (gshift < 12) {
        ngroups = (NT + (1 << gshift) - 1) >> gshift;
        if (65536 + (size_t)B * ngroups * 4 <= ws_size) break;
        ++gshift;
    }
    ngroups = (NT + (1 << gshift) - 1) >> gshift;

    qprep_kernel<<<B, 64, 0, stream>>>(vec, qA);
    initkeys_kernel<<<1024, 256, 0, stream>>>(keys, B * ngroups);
    simgemm_kernel<<<NT, 256, 0, stream>>>(qA, db, sim, keys, N, ngroups, gshift);
    topk_kernel<<<B, 256, 0, stream>>>(sim, keys, out_idx, N, ngroups, gshift);
}